// Round 7
// baseline (123.160 us; speedup 1.0000x reference)
//
#include <hip/hip_runtime.h>
#include <hip/hip_bf16.h>

typedef __attribute__((ext_vector_type(8))) short bf16x8;
typedef __attribute__((ext_vector_type(4))) float f32x4;

#define NB 4096
#define ND 512
#define MARGIN_F 0.2f
#define SENTINEL -3.0e38f

__device__ __forceinline__ void gld_lds16(const void* g, void* l) {
    __builtin_amdgcn_global_load_lds((__attribute__((address_space(1))) void*)g,
                                     (__attribute__((address_space(3))) void*)l,
                                     16, 0, 0);
}

// ---------------------------------------------------------------------------
// Prep: fp32 -> bf16 fragment-swizzled convert (both matrices), grid 2048.
// Block 16 zeroes the finalize accumulators (doneCnt, sum, cnt).
// Swizzle: subtile = 16 rows x 32 cols; si = (row/16)*16 + (col/32);
// lane = (row%16) | (((col%32)/8)<<4); flat = si*512 + lane*8 + j.
// ---------------------------------------------------------------------------
__global__ __launch_bounds__(256) void k_prep(const float* __restrict__ zs,
                                              const float* __restrict__ zi,
                                              __hip_bfloat16* __restrict__ outb,
                                              unsigned int* __restrict__ ctrl) {
    const int bid = blockIdx.x;
    if (bid == 16 && threadIdx.x < 3) ctrl[threadIdx.x] = 0u;   // doneCnt, sumBits, cnt

    int gid = bid * 256 + threadIdx.x;   // [0, 2*4096*64)
    int mat = gid >> 18;                 // 0 = zs, 1 = zi
    int t   = gid & 0x3FFFF;
    int si  = t >> 6;
    int L   = t & 63;
    const float* src = mat ? zi : zs;
    int row = ((si >> 4) << 4) | (L & 15);
    int col = ((si & 15) << 5) | (((L >> 4) & 3) << 3);
    const float4* p = (const float4*)(src + (size_t)row * ND + col);
    float4 f0 = p[0];
    float4 f1 = p[1];
    union { __hip_bfloat16 h[8]; bf16x8 v; } u;
    u.h[0] = __float2bfloat16(f0.x);
    u.h[1] = __float2bfloat16(f0.y);
    u.h[2] = __float2bfloat16(f0.z);
    u.h[3] = __float2bfloat16(f0.w);
    u.h[4] = __float2bfloat16(f1.x);
    u.h[5] = __float2bfloat16(f1.y);
    u.h[6] = __float2bfloat16(f1.z);
    u.h[7] = __float2bfloat16(f1.w);
    bf16x8* dst = (bf16x8*)(outb + ((size_t)mat << 21) + ((size_t)si << 9) + (L << 3));
    *dst = u.v;
}

// ---------------------------------------------------------------------------
// GEMM (S = Zs . Zi^T). Block tile 128x64 (grid 64x32 = 2048), BK=64,
// 4 waves as 2x2: wave tile 64 rows x 32 cols = 4x2 of 16x16x32 bf16 MFMA.
// acc = 32 AGPRs (was 64) so total regs fit the <=128 class ->
// 4 waves/SIMD = 16 waves/CU (R6 post-mortem: 156 regs -> 2 waves/SIMD was
// the latency bottleneck). Epilogue: per-row different-label max over this
// wave's 32 cols -> plain store partial[bx*2+w_n][row]; sentinel = no-neg.
// Blocks with by == bx>>1 extract p_diag.
// ---------------------------------------------------------------------------
__global__ __launch_bounds__(256, 4) void k_gemm_rowmax(const __hip_bfloat16* __restrict__ zsb,
                                                        const __hip_bfloat16* __restrict__ zib,
                                                        const int* __restrict__ labels,
                                                        float* __restrict__ partial,
                                                        float* __restrict__ p_diag) {
    __shared__ __align__(16) unsigned char sA[16384];   // 8 row-sub x 2 k-sub x 1KB
    __shared__ __align__(16) unsigned char sB[8192];    // 4 col-sub x 2 k-sub x 1KB
    __shared__ int labA[128];
    __shared__ int labB[64];

    const int tid = threadIdx.x;
    const int bx = blockIdx.x, by = blockIdx.y;

    if (tid < 128) labA[tid] = labels[by * 128 + tid];
    else if (tid < 192) labB[tid - 128] = labels[bx * 64 + (tid - 128)];

    const char* gA = (const char*)zsb;
    const char* gB = (const char*)zib;
    const int rb0 = tid >> 7;                  // 0/1
    const unsigned int rem = (tid & 127) << 4; // [0,2048): kb*1024 + lane*16
    unsigned int aOff[4], bOff[2];
#pragma unroll
    for (int rd = 0; rd < 4; ++rd)
        aOff[rd] = ((unsigned int)(by * 8 + rd * 2 + rb0) << 14) + rem;
#pragma unroll
    for (int rd = 0; rd < 2; ++rd)
        bOff[rd] = ((unsigned int)(bx * 4 + rd * 2 + rb0) << 14) + rem;

    const int w = tid >> 6, lane = tid & 63;
    const int w_m = w >> 1, w_n = w & 1;
    const int fragOff = lane << 4;

    f32x4 acc[4][2];
#pragma unroll
    for (int i = 0; i < 4; ++i)
#pragma unroll
        for (int j = 0; j < 2; ++j)
            acc[i][j] = (f32x4){0.f, 0.f, 0.f, 0.f};

    for (int ks = 0; ks < 8; ++ks) {
        __syncthreads();
#pragma unroll
        for (int rd = 0; rd < 4; ++rd)
            gld_lds16(gA + aOff[rd] + ks * 2048u, sA + rd * 4096 + (tid << 4));
#pragma unroll
        for (int rd = 0; rd < 2; ++rd)
            gld_lds16(gB + bOff[rd] + ks * 2048u, sB + rd * 4096 + (tid << 4));
        __syncthreads();
#pragma unroll
        for (int kb = 0; kb < 2; ++kb) {
            bf16x8 af[4], bfr[2];
#pragma unroll
            for (int ms = 0; ms < 4; ++ms)
                af[ms] = *(const bf16x8*)(sA + (((w_m * 4 + ms) * 2 + kb) << 10) + fragOff);
#pragma unroll
            for (int ns = 0; ns < 2; ++ns)
                bfr[ns] = *(const bf16x8*)(sB + (((w_n * 2 + ns) * 2 + kb) << 10) + fragOff);
#pragma unroll
            for (int ms = 0; ms < 4; ++ms)
#pragma unroll
                for (int ns = 0; ns < 2; ++ns)
                    acc[ms][ns] = __builtin_amdgcn_mfma_f32_16x16x32_bf16(
                        af[ms], bfr[ns], acc[ms][ns], 0, 0, 0);
        }
    }

    // epilogue: C/D layout col = lane&15, row = (lane>>4)*4 + reg
    const int quad = lane >> 4;
    const int lcol = lane & 15;

    int lb[2];
#pragma unroll
    for (int ns = 0; ns < 2; ++ns)
        lb[ns] = labB[w_n * 32 + ns * 16 + lcol];

    float* slot = partial + ((size_t)(bx * 2 + w_n) << 12) + by * 128 + w_m * 64;

#pragma unroll
    for (int ms = 0; ms < 4; ++ms) {
        int la[4];
#pragma unroll
        for (int r = 0; r < 4; ++r)
            la[r] = labA[w_m * 64 + ms * 16 + quad * 4 + r];
        float mx[4] = {SENTINEL, SENTINEL, SENTINEL, SENTINEL};
#pragma unroll
        for (int ns = 0; ns < 2; ++ns) {
#pragma unroll
            for (int r = 0; r < 4; ++r) {
                float v = acc[ms][ns][r];
                if (la[r] != lb[ns] && v > mx[r]) mx[r] = v;
            }
        }
#pragma unroll
        for (int r = 0; r < 4; ++r) {
            float m = mx[r];
            m = fmaxf(m, __shfl_xor(m, 1));
            m = fmaxf(m, __shfl_xor(m, 2));
            m = fmaxf(m, __shfl_xor(m, 4));
            m = fmaxf(m, __shfl_xor(m, 8));
            if (lcol == 0)
                slot[ms * 16 + quad * 4 + r] = m;
        }
    }

    // diagonal extraction: block covers rows by*128+[0,128), cols bx*64+[0,64).
    // Diag present iff by == bx>>1, held by waves with w_m == (bx&1):
    // row-in-wave j = ms*16 + lcol with ms in {w_n*2, w_n*2+1} (ns = ms - w_n*2).
    if ((bx >> 1) == by && w_m == (bx & 1)) {
        int r = lcol - quad * 4;
        if (r >= 0 && r < 4) {
#pragma unroll
            for (int t = 0; t < 2; ++t) {
                int ms = w_n * 2 + t;
                int rowg = by * 128 + w_m * 64 + ms * 16 + lcol;
                p_diag[rowg] = 1.0f - acc[ms][t][r];
            }
        }
    }
}

// ---------------------------------------------------------------------------
// Finalize: 16 blocks x 256 threads, one row per thread.
// rowbest = max over 128 partial slots; has_neg = rowbest > sentinel;
// per = relu(p - (1 - rowbest) + margin); block sums -> device atomics;
// last of 16 blocks computes the mean and writes out[0].
// ---------------------------------------------------------------------------
__global__ __launch_bounds__(256) void k_finalize(const float* __restrict__ partial,
                                                  const float* __restrict__ p_diag,
                                                  unsigned int* __restrict__ ctrl,
                                                  float* __restrict__ out) {
    const int tid = threadIdx.x;
    const int a = blockIdx.x * 256 + tid;

    float best = SENTINEL;
#pragma unroll 8
    for (int s = 0; s < 128; ++s) {
        float v = partial[((size_t)s << 12) + a];
        best = fmaxf(best, v);
    }

    float sum = 0.0f;
    int cnt = 0;
    if (best > -2.9e38f) {
        float per = p_diag[a] - (1.0f - best) + MARGIN_F;
        if (per > 0.0f) sum = per;
        cnt = 1;
    }

#pragma unroll
    for (int off = 32; off > 0; off >>= 1) {
        sum += __shfl_xor(sum, off);
        cnt += __shfl_xor(cnt, off);
    }
    __shared__ float sSum[4];
    __shared__ int sCnt[4];
    int w = tid >> 6, lane = tid & 63;
    if (lane == 0) { sSum[w] = sum; sCnt[w] = cnt; }
    __syncthreads();

    __shared__ unsigned int sIsLast;
    if (tid == 0) {
        float ts = sSum[0] + sSum[1] + sSum[2] + sSum[3];
        unsigned int tc = (unsigned int)(sCnt[0] + sCnt[1] + sCnt[2] + sCnt[3]);
        atomicAdd((float*)&ctrl[1], ts);
        atomicAdd(&ctrl[2], tc);
        __threadfence();
        unsigned int prev = atomicAdd(&ctrl[0], 1u);
        sIsLast = (prev == 15u) ? 1u : 0u;
    }
    __syncthreads();
    if (sIsLast && tid == 0) {
        __threadfence();
        float ts = atomicAdd((float*)&ctrl[1], 0.0f);
        unsigned int tc = atomicAdd(&ctrl[2], 0u);
        out[0] = (tc > 0u) ? ts / (float)tc : 0.0f;
    }
}

extern "C" void kernel_launch(void* const* d_in, const int* in_sizes, int n_in,
                              void* d_out, int out_size, void* d_ws, size_t ws_size,
                              hipStream_t stream) {
    (void)in_sizes; (void)n_in; (void)out_size; (void)ws_size;
    const float* zs = (const float*)d_in[0];
    const float* zi = (const float*)d_in[1];
    const int* labels = (const int*)d_in[2];
    float* out = (float*)d_out;

    char* ws = (char*)d_ws;
    __hip_bfloat16* zb = (__hip_bfloat16*)ws;                       // 8 MB (zs then zi, swizzled)
    float* partial = (float*)(ws + (8u << 20));                     // 2 MB: [128][4096]
    float* p_diag = (float*)(ws + (10u << 20));                     // 16 KB
    unsigned int* ctrl = (unsigned int*)(ws + (10u << 20) + 16384); // doneCnt, sumBits, cnt

    k_prep<<<2048, 256, 0, stream>>>(zs, zi, zb, ctrl);
    dim3 g(64, 32);
    k_gemm_rowmax<<<g, 256, 0, stream>>>(zb, zb + (size_t)NB * ND, labels, partial, p_diag);
    k_finalize<<<16, 256, 0, stream>>>(partial, p_diag, ctrl, out);
}